// Round 1
// baseline (99.797 us; speedup 1.0000x reference)
//
#include <hip/hip_runtime.h>

#define K 32

__global__ __launch_bounds__(256) void RadiusConnect_kernel(
    const float* __restrict__ src_xyz, const int* __restrict__ batch_src,
    const float* __restrict__ dst_xyz, const int* __restrict__ batch_dst,
    int n_src, int n_dst, int* __restrict__ out)
{
    const int wave = (blockIdx.x * blockDim.x + threadIdx.x) >> 6;
    const int lane = threadIdx.x & 63;
    if (wave >= n_dst) return;
    const int d = wave;

    // dst point + its |dst|^2 with the reference's exact fp32 rounding:
    // sum over last axis left-to-right, no FMA contraction.
    const float xd = dst_xyz[3 * d + 0];
    const float yd = dst_xyz[3 * d + 1];
    const float zd = dst_xyz[3 * d + 2];
    const float d2 = __fadd_rn(__fadd_rn(__fmul_rn(xd, xd), __fmul_rn(yd, yd)),
                               __fmul_rn(zd, zd));
    const int b = batch_dst[d];

    // batch_src is sorted ascending -> same-batch src indices are the
    // contiguous range [start, end). Two lower_bound binary searches
    // (wave-uniform, ~14 iters each).
    int lo = 0, hi = n_src;
    while (lo < hi) {
        int mid = (lo + hi) >> 1;
        if (batch_src[mid] < b) lo = mid + 1; else hi = mid;
    }
    const int start = lo;
    hi = n_src;
    while (lo < hi) {
        int mid = (lo + hi) >> 1;
        if (batch_src[mid] < b + 1) lo = mid + 1; else hi = mid;
    }
    const int end = lo;

    const float rr = __fmul_rn(0.2f, 0.2f);   // exact fp32 R*R as in reference
    int* __restrict__ out_src = out;
    int* __restrict__ out_dst = out + (size_t)n_dst * K;
    const long long base = (long long)d * K;

    int count = 0;  // wave-uniform running count of valid neighbors found
    for (int j0 = start; j0 < end && count < K; j0 += 64) {
        const int j = j0 + lane;
        bool valid = false;
        if (j < end) {
            const float xs = src_xyz[3 * j + 0];
            const float ys = src_xyz[3 * j + 1];
            const float zs = src_xyz[3 * j + 2];
            // Reference: dist2 = (d2 + s2) - 2*cross, all fp32, no contraction.
            const float s2 = __fadd_rn(
                __fadd_rn(__fmul_rn(xs, xs), __fmul_rn(ys, ys)),
                __fmul_rn(zs, zs));
            const float cross = __fadd_rn(
                __fadd_rn(__fmul_rn(xd, xs), __fmul_rn(yd, ys)),
                __fmul_rn(zd, zs));
            const float dist2 = __fsub_rn(__fadd_rn(d2, s2),
                                          __fmul_rn(2.0f, cross));
            valid = (dist2 <= rr);
        }
        const unsigned long long mask = __ballot(valid);
        const int pre = __popcll(mask & ((1ull << lane) - 1ull));
        const int rank = count + pre;
        if (valid && rank < K) {
            out_src[base + rank] = j;
            out_dst[base + rank] = d;
        }
        count += __popcll(mask);
    }

    // Pad the unfilled tail with -1 (d_out is poisoned 0xAA before each call).
    if (count < K && lane >= count && lane < K) {
        out_src[base + lane] = -1;
        out_dst[base + lane] = -1;
    }
}

extern "C" void kernel_launch(void* const* d_in, const int* in_sizes, int n_in,
                              void* d_out, int out_size, void* d_ws, size_t ws_size,
                              hipStream_t stream) {
    const float* src_xyz   = (const float*)d_in[0];
    const int*   batch_src = (const int*)d_in[1];
    const float* dst_xyz   = (const float*)d_in[2];
    const int*   batch_dst = (const int*)d_in[3];
    int* out = (int*)d_out;

    const int n_src = in_sizes[0] / 3;
    const int n_dst = in_sizes[2] / 3;

    const int threads = 256;                      // 4 waves/block
    const int blocks = (n_dst * 64 + threads - 1) / threads;
    RadiusConnect_kernel<<<blocks, threads, 0, stream>>>(
        src_xyz, batch_src, dst_xyz, batch_dst, n_src, n_dst, out);
}

// Round 2
// 87.092 us; speedup vs baseline: 1.1459x; 1.1459x over previous
//
#include <hip/hip_runtime.h>

#define K 32
#define NB 8          // number of batches (values 0..NB-1)

// One-shot: bounds[b] = lower_bound(batch_src, b) for b in [0, NB]; bounds[NB]=n_src.
__global__ void bounds_kernel(const int* __restrict__ batch_src, int n_src,
                              int* __restrict__ bounds) {
    const int b = threadIdx.x;
    if (b > NB) return;
    int lo = 0, hi = n_src;
    while (lo < hi) {
        int mid = (lo + hi) >> 1;
        if (batch_src[mid] < b) lo = mid + 1; else hi = mid;
    }
    bounds[b] = lo;
}

__global__ __launch_bounds__(256) void RadiusConnect_kernel(
    const float* __restrict__ src_xyz,
    const float* __restrict__ dst_xyz, const int* __restrict__ batch_dst,
    const int* __restrict__ bounds,
    int n_dst, int* __restrict__ out)
{
    const int wave = (blockIdx.x * blockDim.x + threadIdx.x) >> 6;
    const int lane = threadIdx.x & 63;
    if (wave >= n_dst) return;
    const int d = wave;

    // dst point + |dst|^2 with the reference's exact fp32 rounding
    // (left-to-right adds, no FMA contraction).
    const float xd = dst_xyz[3 * d + 0];
    const float yd = dst_xyz[3 * d + 1];
    const float zd = dst_xyz[3 * d + 2];
    const float d2 = __fadd_rn(__fadd_rn(__fmul_rn(xd, xd), __fmul_rn(yd, yd)),
                               __fmul_rn(zd, zd));
    const int b = batch_dst[d];
    const int start = bounds[b];
    const int end   = bounds[b + 1];

    const float rr = __fmul_rn(0.2f, 0.2f);
    int* __restrict__ out_src = out;
    int* __restrict__ out_dst = out + (size_t)n_dst * K;
    const long long base = (long long)d * K;
    const unsigned long long lt_mask = (1ull << lane) - 1ull;

    int count = 0;  // wave-uniform count of valid neighbors found so far
    for (int j0 = start; j0 < end && count < K; j0 += 256) {
        // ---- issue all 12 loads up front (independent, coalesced) ----
        float xs[4], ys[4], zs[4];
        int jj[4];
#pragma unroll
        for (int g = 0; g < 4; ++g) {
            int j = j0 + g * 64 + lane;
            jj[g] = j;
            int jl = j < end ? j : end - 1;   // clamp: always a legal address
            xs[g] = src_xyz[3 * jl + 0];
            ys[g] = src_xyz[3 * jl + 1];
            zs[g] = src_xyz[3 * jl + 2];
        }
        // ---- distances + validity (reference-exact fp32 rounding) ----
        bool valid[4];
#pragma unroll
        for (int g = 0; g < 4; ++g) {
            const float s2 = __fadd_rn(
                __fadd_rn(__fmul_rn(xs[g], xs[g]), __fmul_rn(ys[g], ys[g])),
                __fmul_rn(zs[g], zs[g]));
            const float cross = __fadd_rn(
                __fadd_rn(__fmul_rn(xd, xs[g]), __fmul_rn(yd, ys[g])),
                __fmul_rn(zd, zs[g]));
            const float dist2 = __fsub_rn(__fadd_rn(d2, s2),
                                          __fmul_rn(2.0f, cross));
            valid[g] = (jj[g] < end) && (dist2 <= rr);
        }
        // ---- rank assignment in index order, early-exit via count ----
#pragma unroll
        for (int g = 0; g < 4; ++g) {
            const unsigned long long mask = __ballot(valid[g]);
            const int rank = count + __popcll(mask & lt_mask);
            if (valid[g] && rank < K) {
                out_src[base + rank] = jj[g];
                out_dst[base + rank] = d;
            }
            count += __popcll(mask);
        }
    }

    // Pad unfilled tail with -1 (d_out is re-poisoned before every call).
    if (count < K && lane >= count && lane < K) {
        out_src[base + lane] = -1;
        out_dst[base + lane] = -1;
    }
}

extern "C" void kernel_launch(void* const* d_in, const int* in_sizes, int n_in,
                              void* d_out, int out_size, void* d_ws, size_t ws_size,
                              hipStream_t stream) {
    const float* src_xyz   = (const float*)d_in[0];
    const int*   batch_src = (const int*)d_in[1];
    const float* dst_xyz   = (const float*)d_in[2];
    const int*   batch_dst = (const int*)d_in[3];
    int* out    = (int*)d_out;
    int* bounds = (int*)d_ws;     // NB+1 ints

    const int n_src = in_sizes[0] / 3;
    const int n_dst = in_sizes[2] / 3;

    bounds_kernel<<<1, 16, 0, stream>>>(batch_src, n_src, bounds);

    const int threads = 256;                      // 4 waves/block
    const int blocks = (n_dst * 64 + threads - 1) / threads;
    RadiusConnect_kernel<<<blocks, threads, 0, stream>>>(
        src_xyz, dst_xyz, batch_dst, bounds, n_dst, out);
}